// Round 1
// 338.167 us; speedup vs baseline: 1.4659x; 1.4659x over previous
//
#include <hip/hip_runtime.h>

#define N_IN 128
#define HID 256
#define NB 16
#define BM 128
#define HS_STRIDE 264   // bf16 row stride for H tile (16B pad -> 2-way banks only, free)
#define BS_STRIDE 17    // basis LDS stride (f32)

typedef __attribute__((ext_vector_type(8))) short s8v;   // 8 bf16 = 4 VGPRs
typedef __attribute__((ext_vector_type(4))) float f4v;   // MFMA 16x16x32 accumulator

__device__ __forceinline__ unsigned short f2bf(float f) {
  unsigned int u = __float_as_uint(f);
  u += 0x7fffu + ((u >> 16) & 1u);   // round-to-nearest-even
  return (unsigned short)(u >> 16);
}

__device__ __forceinline__ float tanh_fast(float x) {
  float e = __expf(2.0f * x);
  return 1.0f - 2.0f * __builtin_amdgcn_rcpf(e + 1.0f);
}

// Fragment-ordered bf16 repack (1 KB coalesced MFMA fragments), as round 2.
// W1f frag (pass,kk,ct): n = pass*128+ct*16+l15, k = kk*32+quad*8+j, val = W1[k*256+n]
// W2f frag (b,kk,ct):    n = ct*16+l15,          k = kk*32+quad*8+j, val = W2[k*2048+n*16+b]
__global__ void prep_kernel(const float* __restrict__ W1, const float* __restrict__ W2,
                            unsigned short* __restrict__ W1f, unsigned short* __restrict__ W2f) {
  int tid = blockIdx.x * blockDim.x + threadIdx.x;
  if (tid < N_IN * HID) {
    int j = tid & 7, lane = (tid >> 3) & 63, ct = (tid >> 9) & 7, kk = (tid >> 12) & 3, pass = tid >> 14;
    int n = pass * 128 + ct * 16 + (lane & 15);
    int k = kk * 32 + (lane >> 4) * 8 + j;
    W1f[tid] = f2bf(W1[k * HID + n]);
  }
  int i = tid - N_IN * HID;
  if (i >= 0 && i < HID * (N_IN * NB)) {
    int j = i & 7, lane = (i >> 3) & 63, ct = (i >> 9) & 7, kk = (i >> 12) & 7, b = i >> 15;
    int n = ct * 16 + (lane & 15);
    int k = kk * 32 + (lane >> 4) * 8 + j;
    W2f[i] = f2bf(W2[k * (N_IN * NB) + n * 16 + b]);
  }
}

__global__ void __launch_bounds__(256, 2)
pilayer_kernel(const float* __restrict__ prop,
               const int* __restrict__ idx_i,
               const int* __restrict__ idx_j,
               const float* __restrict__ basis,
               const unsigned short* __restrict__ W1f,
               const unsigned short* __restrict__ W2f,
               float* __restrict__ out, int P) {
  __shared__ unsigned short Hs[BM * HS_STRIDE];   // 67,584 B (live through phase C)
  __shared__ float basisS[BM * BS_STRIDE];        //  8,704 B  -> 76.3 KB, 2 blocks/CU

  const int t = threadIdx.x;
  const int lane = t & 63;
  const int wv = t >> 6;
  const int l15 = lane & 15;
  const int l4 = lane >> 4;
  const int tile0 = blockIdx.x * BM;
  const int row0 = wv * 32;

  // ---- edge indices at kernel top: head of the idx->prop pointer-chase,
  //      overlaps basis staging below ----
  int pidx[2], qidx[2];
#pragma unroll
  for (int rt = 0; rt < 2; ++rt) {
    int p = tile0 + row0 + rt * 16 + l15; if (p >= P) p = P - 1;
    pidx[rt] = idx_i[p];
    qidx[rt] = idx_j[p];
  }

  // ---- stage basis tile cooperatively (nt loads: basis streamed exactly once) ----
  {
    int r = t >> 1;
    int c0 = (t & 1) * 8;
    int p = tile0 + r; if (p >= P) p = P - 1;
    const f4v* bp = (const f4v*)(basis + (long)p * NB + c0);
    f4v b0 = __builtin_nontemporal_load(bp);
    f4v b1 = __builtin_nontemporal_load(bp + 1);
    float* dst = &basisS[r * BS_STRIDE + c0];
    dst[0] = b0[0]; dst[1] = b0[1]; dst[2] = b0[2]; dst[3] = b0[3];
    dst[4] = b1[0]; dst[5] = b1[1]; dst[6] = b1[2]; dst[7] = b1[3];
  }

  // ---- Phase B: wave wv computes H rows [32*wv, 32*wv+32), all 256 cols ----
  // Gathers hoisted OUT of the pass loop: issued once (was 2x), reused by both passes.
  {
    s8v afr[4][2];   // [kk][rt] A fragments, 32 VGPR, live through both passes
#pragma unroll
    for (int kk = 0; kk < 4; ++kk) {
      int k0 = kk * 32 + l4 * 8;
#pragma unroll
      for (int rt = 0; rt < 2; ++rt) {
        const float4* ai = (const float4*)(prop + (long)pidx[rt] * N_IN + k0);
        const float4* aj = (const float4*)(prop + (long)qidx[rt] * N_IN + k0);
        float4 x0 = ai[0], x1 = ai[1];
        float4 y0 = aj[0], y1 = aj[1];
        s8v a;
        a[0] = (short)f2bf(x0.x + y0.x); a[1] = (short)f2bf(x0.y + y0.y);
        a[2] = (short)f2bf(x0.z + y0.z); a[3] = (short)f2bf(x0.w + y0.w);
        a[4] = (short)f2bf(x1.x + y1.x); a[5] = (short)f2bf(x1.y + y1.y);
        a[6] = (short)f2bf(x1.z + y1.z); a[7] = (short)f2bf(x1.w + y1.w);
        afr[kk][rt] = a;
      }
    }
#pragma unroll
    for (int pass = 0; pass < 2; ++pass) {
      f4v acc[2][8];
#pragma unroll
      for (int rt = 0; rt < 2; ++rt)
#pragma unroll
        for (int ct = 0; ct < 8; ++ct) acc[rt][ct] = (f4v){0.f, 0.f, 0.f, 0.f};
#pragma unroll
      for (int kk = 0; kk < 4; ++kk) {
#pragma unroll
        for (int ct = 0; ct < 8; ++ct) {
          s8v bfr = *(const s8v*)(W1f + ((((pass * 4 + kk) * 8 + ct) * 64 + lane) << 3));
#pragma unroll
          for (int rt = 0; rt < 2; ++rt)
            acc[rt][ct] = __builtin_amdgcn_mfma_f32_16x16x32_bf16(afr[kk][rt], bfr, acc[rt][ct], 0, 0, 0);
        }
      }
#pragma unroll
      for (int rt = 0; rt < 2; ++rt)
#pragma unroll
        for (int ct = 0; ct < 8; ++ct)
#pragma unroll
          for (int r = 0; r < 4; ++r) {
            int lrow = row0 + rt * 16 + l4 * 4 + r;
            int col = pass * 128 + ct * 16 + l15;
            Hs[lrow * HS_STRIDE + col] = f2bf(tanh_fast(acc[rt][ct][r]));
          }
    }
  }

  __syncthreads();   // H + basis visible to all waves

  // ---- Phase C: 2x2 wave partition; wave (rg,cg) owns rows rg*64..+64, cols cg*64..+64.
  // A (H) cached in registers per K-half; B prefetched from global W2f at DISTANCE 3
  // (ring of 4 slot-sets, slot index = compile-time q) -> 12 loads in flight, covers
  // L3-latency B fetches that the old 1-deep prefetch could not hide.
  const int rg = wv >> 1, cg = wv & 1;
  const int rbase = rg * 64;

  f4v o[4][4];   // [rt][q] -> rows rbase+rt*16.., cols (cg*4+q)*16..
#pragma unroll
  for (int rt = 0; rt < 4; ++rt)
#pragma unroll
    for (int q = 0; q < 4; ++q) o[rt][q] = (f4v){0.f, 0.f, 0.f, 0.f};

#pragma unroll 1
  for (int khalf = 0; khalf < 2; ++khalf) {
    // A-cache: 16 fragments (64 VGPR), reused across all 16 b and 4 q
    s8v areg[4][4];   // [rt][kloc]
#pragma unroll
    for (int rt = 0; rt < 4; ++rt)
#pragma unroll
      for (int kloc = 0; kloc < 4; ++kloc)
        areg[rt][kloc] = *(const s8v*)&Hs[(rbase + rt * 16 + l15) * HS_STRIDE +
                                          (khalf * 4 + kloc) * 32 + l4 * 8];

    s8v bf[4][4];   // register ring of B fragments [slot][kloc], slot = it & 3
    // preload iterations 0,1,2  (b=0, q=0..2)
#pragma unroll
    for (int q0 = 0; q0 < 3; ++q0)
#pragma unroll
      for (int kloc = 0; kloc < 4; ++kloc)
        bf[q0][kloc] = *(const s8v*)(W2f +
            ((((khalf * 4 + kloc) * 8) + cg * 4 + q0) << 9) + lane * 8);

#pragma unroll 1
    for (int b = 0; b < 16; ++b) {
      float bs[4][4];
#pragma unroll
      for (int rt = 0; rt < 4; ++rt)
#pragma unroll
        for (int r = 0; r < 4; ++r)
          bs[rt][r] = basisS[(rbase + rt * 16 + l4 * 4 + r) * BS_STRIDE + b];

#pragma unroll
      for (int q = 0; q < 4; ++q) {
        // prefetch iteration it+3 into slot (q+3)&3  (it = b*4+q)
        {
          int nb = b + ((q + 3) >> 2); if (nb > 15) nb = 15;   // tail: harmless re-read
          int nq = (q + 3) & 3;
#pragma unroll
          for (int kloc = 0; kloc < 4; ++kloc)
            bf[(q + 3) & 3][kloc] = *(const s8v*)(W2f +
                (((nb * 8 + khalf * 4 + kloc) * 8 + cg * 4 + nq) << 9) + lane * 8);
        }
        f4v g[4];
#pragma unroll
        for (int rt = 0; rt < 4; ++rt) g[rt] = (f4v){0.f, 0.f, 0.f, 0.f};
        __builtin_amdgcn_s_setprio(1);   // T5: barrier-free independent waves
#pragma unroll
        for (int kloc = 0; kloc < 4; ++kloc)
#pragma unroll
          for (int rt = 0; rt < 4; ++rt)
            g[rt] = __builtin_amdgcn_mfma_f32_16x16x32_bf16(areg[rt][kloc], bf[q][kloc], g[rt], 0, 0, 0);
        __builtin_amdgcn_s_setprio(0);
#pragma unroll
        for (int rt = 0; rt < 4; ++rt)
#pragma unroll
          for (int r = 0; r < 4; ++r)
            o[rt][q][r] += g[rt][r] * bs[rt][r];
      }
    }
  }

  // ---- epilogue: out[p][c], c = (cg*4+q)*16 + l15. Non-temporal: out is
  // write-once/never-read -> keep it from evicting W2f out of L2. ----
#pragma unroll
  for (int rt = 0; rt < 4; ++rt)
#pragma unroll
    for (int r = 0; r < 4; ++r) {
      int p = tile0 + rbase + rt * 16 + l4 * 4 + r;
      if (p < P) {
        float* op = out + (long)p * N_IN + cg * 64 + l15;
#pragma unroll
        for (int q = 0; q < 4; ++q)
          __builtin_nontemporal_store(o[rt][q][r], op + q * 16);
      }
    }
}

extern "C" void kernel_launch(void* const* d_in, const int* in_sizes, int n_in,
                              void* d_out, int out_size, void* d_ws, size_t ws_size,
                              hipStream_t stream) {
  const float* prop  = (const float*)d_in[0];
  const int* idx_i   = (const int*)d_in[1];
  const int* idx_j   = (const int*)d_in[2];
  const float* basis = (const float*)d_in[3];
  const float* W1    = (const float*)d_in[4];
  const float* W2    = (const float*)d_in[5];
  float* out = (float*)d_out;
  int P = in_sizes[1];

  unsigned short* W1f = (unsigned short*)d_ws;                 // 32768 bf16
  unsigned short* W2f = W1f + N_IN * HID;                      // 524288 bf16

  int prep_threads = N_IN * HID + HID * N_IN * NB;             // 557056
  prep_kernel<<<(prep_threads + 255) / 256, 256, 0, stream>>>(W1, W2, W1f, W2f);

  int ntiles = (P + BM - 1) / BM;
  pilayer_kernel<<<ntiles, 256, 0, stream>>>(prop, idx_i, idx_j, basis, W1f, W2f, out, P);
}